// Round 2
// baseline (1696.910 us; speedup 1.0000x reference)
//
#include <hip/hip_runtime.h>

#define N_NODES 100000
#define D 64  // DIN == DOUT == 64

// ---------------------------------------------------------------------------
// Kernel 1: edge scatter.  16 lanes per edge; lane q handles dims [4q, 4q+4).
//   accum[dst[e]][d] += feature[src[e]][d] * norm[src[e]]   (fp32 HW atomics)
// ---------------------------------------------------------------------------
__global__ __launch_bounds__(256) void edge_scatter_kernel(
    const float* __restrict__ feature,  // [N, 64] fp32
    const float* __restrict__ norm,     // [N]     fp32
    const int* __restrict__ src,        // [E]
    const int* __restrict__ dst,        // [E]
    float* __restrict__ accum,          // [N, 64] fp32 (ws)
    int E)
{
    long long gid = (long long)blockIdx.x * blockDim.x + threadIdx.x;
    int e = (int)(gid >> 4);        // edge index
    int q = (int)(gid & 15);        // quad index within the 64-dim row
    if (e >= E) return;

    int s = src[e];
    int t = dst[e];
    float nv = norm[s];

    const float4 f = *(const float4*)&feature[s * D + q * 4];
    float* a = &accum[t * D + q * 4];

    unsafeAtomicAdd(a + 0, f.x * nv);
    unsafeAtomicAdd(a + 1, f.y * nv);
    unsafeAtomicAdd(a + 2, f.z * nv);
    unsafeAtomicAdd(a + 3, f.w * nv);
}

// ---------------------------------------------------------------------------
// Kernel 2: per-node renorm + linear.  One wave per node, lane o = out dim.
//   out[n][o] = sum_k (accum[n][k] * norm[n]) * W[o][k] + b[o]
// W staged in LDS transposed (Wt[k][o]) so the k-loop reads are
// consecutive-lane -> consecutive-bank (2 lanes/bank aliasing = free).
// ---------------------------------------------------------------------------
__global__ __launch_bounds__(256) void node_linear_kernel(
    const float* __restrict__ accum,    // [N, 64] fp32 (ws)
    const float* __restrict__ norm,     // [N] fp32
    const float* __restrict__ W,        // [64, 64] fp32, row-major [o][k]
    const float* __restrict__ b,        // [64] fp32
    float* __restrict__ out)            // [N, 64] fp32
{
    __shared__ float Wt[D * D];  // Wt[k*64 + o] = W[o*64 + k]

    for (int i = threadIdx.x; i < D * D; i += blockDim.x) {
        int o = i >> 6;
        int k = i & 63;
        Wt[k * D + o] = W[o * D + k];
    }
    __syncthreads();

    int node = (blockIdx.x * blockDim.x + threadIdx.x) >> 6;
    int lane = threadIdx.x & 63;
    if (node >= N_NODES) return;

    float nv = norm[node];
    float a  = accum[node * D + lane] * nv;   // lane holds a[lane]

    float acc = b[lane];
    #pragma unroll
    for (int k = 0; k < D; ++k) {
        float ak = __shfl(a, k, 64);          // broadcast a[k] across the wave
        acc = fmaf(ak, Wt[k * D + lane], acc);
    }
    out[node * D + lane] = acc;
}

extern "C" void kernel_launch(void* const* d_in, const int* in_sizes, int n_in,
                              void* d_out, int out_size, void* d_ws, size_t ws_size,
                              hipStream_t stream)
{
    const float* feature = (const float*)d_in[0];  // [N,64] fp32
    const float* norm    = (const float*)d_in[1];  // [N,1]  fp32
    const int*   src     = (const int*)d_in[2];    // [E]
    const int*   dst     = (const int*)d_in[3];    // [E]
    const float* W       = (const float*)d_in[4];  // [64,64] fp32
    const float* b       = (const float*)d_in[5];  // [64]   fp32
    float*       out     = (float*)d_out;          // [N,64] fp32

    const int E = in_sizes[2];

    float* accum = (float*)d_ws;                   // N*64 fp32 = 25.6 MB
    size_t accum_bytes = (size_t)N_NODES * D * sizeof(float);

    // ws is re-poisoned to 0xAA before every call; zero the accumulator.
    hipMemsetAsync(accum, 0, accum_bytes, stream);

    // Edge scatter: 16 lanes per edge.
    {
        long long total = (long long)E * 16;
        int block = 256;
        int grid  = (int)((total + block - 1) / block);
        edge_scatter_kernel<<<grid, block, 0, stream>>>(feature, norm, src, dst,
                                                        accum, E);
    }

    // Node linear: one wave per node.
    {
        long long total = (long long)N_NODES * 64;
        int block = 256;
        int grid  = (int)((total + block - 1) / block);
        node_linear_kernel<<<grid, block, 0, stream>>>(accum, norm, W, b, out);
    }
}

// Round 3
// 540.649 us; speedup vs baseline: 3.1387x; 3.1387x over previous
//
#include <hip/hip_runtime.h>

#define N_NODES 100000
#define D 64            // DIN == DOUT == 64
#define SCAN_BLOCK 256
#define SCAN_ITEMS 8                       // elements per thread
#define SCAN_CHUNK (SCAN_BLOCK * SCAN_ITEMS)  // 2048 per block
#define NUM_SCAN_BLOCKS ((N_NODES + SCAN_CHUNK - 1) / SCAN_CHUNK)  // 49

// ---------------------------------------------------------------------------
// k1: degree histogram over dst.  3.2M cheap int atomics total (k1+k5),
// replacing 102.4M write-through fp32 atomics of the scatter formulation.
// ---------------------------------------------------------------------------
__global__ __launch_bounds__(256) void histogram_kernel(
    const int* __restrict__ dst, int* __restrict__ deg, int E)
{
    int e = blockIdx.x * blockDim.x + threadIdx.x;
    if (e < E) atomicAdd(&deg[dst[e]], 1);
}

// ---------------------------------------------------------------------------
// k2: per-block exclusive scan of deg (2048 elems/block) + block totals.
// ---------------------------------------------------------------------------
__global__ __launch_bounds__(SCAN_BLOCK) void scan_blocks_kernel(
    const int* __restrict__ deg, int* __restrict__ offs, int* __restrict__ blocksum)
{
    __shared__ int sm[SCAN_BLOCK];
    int base = blockIdx.x * SCAN_CHUNK + threadIdx.x * SCAN_ITEMS;
    int vals[SCAN_ITEMS];
    int tot = 0;
    #pragma unroll
    for (int i = 0; i < SCAN_ITEMS; ++i) {
        int idx = base + i;
        int v = (idx < N_NODES) ? deg[idx] : 0;
        vals[i] = tot;          // thread-local exclusive prefix
        tot += v;
    }
    int x = tot;                // inclusive scan of per-thread totals
    sm[threadIdx.x] = x;
    __syncthreads();
    for (int off = 1; off < SCAN_BLOCK; off <<= 1) {
        int y = (threadIdx.x >= off) ? sm[threadIdx.x - off] : 0;
        __syncthreads();
        x += y;
        sm[threadIdx.x] = x;
        __syncthreads();
    }
    int excl = x - tot;         // block-level exclusive prefix for this thread
    if (threadIdx.x == SCAN_BLOCK - 1) blocksum[blockIdx.x] = x;
    #pragma unroll
    for (int i = 0; i < SCAN_ITEMS; ++i) {
        int idx = base + i;
        if (idx < N_NODES) offs[idx] = excl + vals[i];
    }
}

// ---------------------------------------------------------------------------
// k3: exclusive scan of the 49 block sums (single wave, shfl scan).
// ---------------------------------------------------------------------------
__global__ void scan_blocksums_kernel(int* __restrict__ blocksum)
{
    int tid = threadIdx.x;  // launched with 64 threads
    int v = (tid < NUM_SCAN_BLOCKS) ? blocksum[tid] : 0;
    int orig = v;
    #pragma unroll
    for (int off = 1; off < 64; off <<= 1) {
        int y = __shfl_up(v, off, 64);
        if (tid >= off) v += y;
    }
    if (tid < NUM_SCAN_BLOCKS) blocksum[tid] = v - orig;  // exclusive
}

// ---------------------------------------------------------------------------
// k4: add block offsets -> global exclusive offs; init cursor = offs.
// ---------------------------------------------------------------------------
__global__ __launch_bounds__(256) void add_offsets_kernel(
    int* __restrict__ offs, const int* __restrict__ blocksum, int* __restrict__ cursor)
{
    int idx = blockIdx.x * blockDim.x + threadIdx.x;
    if (idx < N_NODES) {
        int v = offs[idx] + blocksum[idx / SCAN_CHUNK];
        offs[idx]  = v;
        cursor[idx] = v;
    }
}

// ---------------------------------------------------------------------------
// k5: scatter edge source indices into CSR slots (counting-sort placement).
// After this, cursor[n] == offs[n] + deg[n] == end of node n's edge list.
// ---------------------------------------------------------------------------
__global__ __launch_bounds__(256) void build_csr_kernel(
    const int* __restrict__ src, const int* __restrict__ dst,
    int* __restrict__ cursor, int* __restrict__ csr_src, int E)
{
    int e = blockIdx.x * blockDim.x + threadIdx.x;
    if (e < E) {
        int pos = atomicAdd(&cursor[dst[e]], 1);
        csr_src[pos] = src[e];
    }
}

// ---------------------------------------------------------------------------
// k6: fused gather + renorm + linear.  One wave per node, lane = dim.
//   acc[lane] = norm[n] * sum_{s in in(n)} feature[s][lane] * norm[s]
//   out[n][o=lane] = b[o] + sum_k acc[k] * W[o][k]
// Each edge read is one coalesced 256B row load.  W staged in LDS transposed
// (Wt[k][o]) so lane reads are stride-1 (2 lanes/bank = free).
// ---------------------------------------------------------------------------
__global__ __launch_bounds__(256) void gather_linear_kernel(
    const float* __restrict__ feature,  // [N, 64]
    const float* __restrict__ norm,     // [N]
    const int* __restrict__ offs,       // [N] exclusive start
    const int* __restrict__ endp,       // [N] end (cursor after build_csr)
    const int* __restrict__ csr_src,    // [E]
    const float* __restrict__ W,        // [64, 64] row-major [o][k]
    const float* __restrict__ b,        // [64]
    float* __restrict__ out)            // [N, 64]
{
    __shared__ float Wt[D * D];
    for (int i = threadIdx.x; i < D * D; i += blockDim.x) {
        int o = i >> 6, k = i & 63;
        Wt[k * D + o] = W[o * D + k];
    }
    __syncthreads();

    int node = (blockIdx.x * blockDim.x + threadIdx.x) >> 6;
    int lane = threadIdx.x & 63;
    if (node >= N_NODES) return;

    int beg = offs[node];
    int end = endp[node];

    // Gather-accumulate, unrolled x4 for memory-level parallelism.
    float acc = 0.f;
    int i = beg;
    for (; i + 4 <= end; i += 4) {
        int s0 = csr_src[i + 0];
        int s1 = csr_src[i + 1];
        int s2 = csr_src[i + 2];
        int s3 = csr_src[i + 3];
        float f0 = feature[s0 * D + lane], n0 = norm[s0];
        float f1 = feature[s1 * D + lane], n1 = norm[s1];
        float f2 = feature[s2 * D + lane], n2 = norm[s2];
        float f3 = feature[s3 * D + lane], n3 = norm[s3];
        acc = fmaf(f0, n0, acc);
        acc = fmaf(f1, n1, acc);
        acc = fmaf(f2, n2, acc);
        acc = fmaf(f3, n3, acc);
    }
    for (; i < end; ++i) {
        int s = csr_src[i];
        acc = fmaf(feature[s * D + lane], norm[s], acc);
    }
    acc *= norm[node];

    // Matvec: lane o accumulates over k via wave broadcast of acc[k].
    float r = b[lane];
    #pragma unroll
    for (int k = 0; k < D; ++k) {
        float ak = __shfl(acc, k, 64);
        r = fmaf(ak, Wt[k * D + lane], r);
    }
    out[node * D + lane] = r;
}

extern "C" void kernel_launch(void* const* d_in, const int* in_sizes, int n_in,
                              void* d_out, int out_size, void* d_ws, size_t ws_size,
                              hipStream_t stream)
{
    const float* feature = (const float*)d_in[0];  // [N,64]
    const float* norm    = (const float*)d_in[1];  // [N,1]
    const int*   src     = (const int*)d_in[2];    // [E]
    const int*   dst     = (const int*)d_in[3];    // [E]
    const float* W       = (const float*)d_in[4];  // [64,64]
    const float* b       = (const float*)d_in[5];  // [64]
    float*       out     = (float*)d_out;          // [N,64]

    const int E = in_sizes[2];

    // ws layout (all int32): deg[N] | offs[N] | cursor[N] | blocksum[49] | csr_src[E]
    int* deg      = (int*)d_ws;
    int* offs     = deg + N_NODES;
    int* cursor   = offs + N_NODES;
    int* blocksum = cursor + N_NODES;
    int* csr_src  = blocksum + ((NUM_SCAN_BLOCKS + 63) & ~63);  // keep csr aligned

    hipMemsetAsync(deg, 0, (size_t)N_NODES * sizeof(int), stream);

    histogram_kernel<<<(E + 255) / 256, 256, 0, stream>>>(dst, deg, E);

    scan_blocks_kernel<<<NUM_SCAN_BLOCKS, SCAN_BLOCK, 0, stream>>>(deg, offs, blocksum);
    scan_blocksums_kernel<<<1, 64, 0, stream>>>(blocksum);
    add_offsets_kernel<<<(N_NODES + 255) / 256, 256, 0, stream>>>(offs, blocksum, cursor);

    build_csr_kernel<<<(E + 255) / 256, 256, 0, stream>>>(src, dst, cursor, csr_src, E);

    long long total = (long long)N_NODES * 64;
    gather_linear_kernel<<<(int)((total + 255) / 256), 256, 0, stream>>>(
        feature, norm, offs, cursor, csr_src, W, b, out);
}

// Round 4
// 399.850 us; speedup vs baseline: 4.2439x; 1.3521x over previous
//
#include <hip/hip_runtime.h>

#define N_NODES 100000
#define D 64            // DIN == DOUT == 64
#define DP 65           // padded leading dim for the LDS transpose of W
#define SCAN_BLOCK 256
#define SCAN_ITEMS 8                       // elements per thread
#define SCAN_CHUNK (SCAN_BLOCK * SCAN_ITEMS)  // 2048 per block
#define NUM_SCAN_BLOCKS ((N_NODES + SCAN_CHUNK - 1) / SCAN_CHUNK)  // 49

// ---------------------------------------------------------------------------
// k1: degree histogram over dst.
// ---------------------------------------------------------------------------
__global__ __launch_bounds__(256) void histogram_kernel(
    const int* __restrict__ dst, int* __restrict__ deg, int E)
{
    int e = blockIdx.x * blockDim.x + threadIdx.x;
    if (e < E) atomicAdd(&deg[dst[e]], 1);
}

// ---------------------------------------------------------------------------
// k2: per-block exclusive scan of deg (2048 elems/block) + block totals.
// ---------------------------------------------------------------------------
__global__ __launch_bounds__(SCAN_BLOCK) void scan_blocks_kernel(
    const int* __restrict__ deg, int* __restrict__ offs, int* __restrict__ blocksum)
{
    __shared__ int sm[SCAN_BLOCK];
    int base = blockIdx.x * SCAN_CHUNK + threadIdx.x * SCAN_ITEMS;
    int vals[SCAN_ITEMS];
    int tot = 0;
    #pragma unroll
    for (int i = 0; i < SCAN_ITEMS; ++i) {
        int idx = base + i;
        int v = (idx < N_NODES) ? deg[idx] : 0;
        vals[i] = tot;          // thread-local exclusive prefix
        tot += v;
    }
    int x = tot;                // inclusive scan of per-thread totals
    sm[threadIdx.x] = x;
    __syncthreads();
    for (int off = 1; off < SCAN_BLOCK; off <<= 1) {
        int y = (threadIdx.x >= off) ? sm[threadIdx.x - off] : 0;
        __syncthreads();
        x += y;
        sm[threadIdx.x] = x;
        __syncthreads();
    }
    int excl = x - tot;         // block-level exclusive prefix for this thread
    if (threadIdx.x == SCAN_BLOCK - 1) blocksum[blockIdx.x] = x;
    #pragma unroll
    for (int i = 0; i < SCAN_ITEMS; ++i) {
        int idx = base + i;
        if (idx < N_NODES) offs[idx] = excl + vals[i];
    }
}

// ---------------------------------------------------------------------------
// k3: exclusive scan of the 49 block sums (single wave, shfl scan).
// ---------------------------------------------------------------------------
__global__ void scan_blocksums_kernel(int* __restrict__ blocksum)
{
    int tid = threadIdx.x;  // launched with 64 threads
    int v = (tid < NUM_SCAN_BLOCKS) ? blocksum[tid] : 0;
    int orig = v;
    #pragma unroll
    for (int off = 1; off < 64; off <<= 1) {
        int y = __shfl_up(v, off, 64);
        if (tid >= off) v += y;
    }
    if (tid < NUM_SCAN_BLOCKS) blocksum[tid] = v - orig;  // exclusive
}

// ---------------------------------------------------------------------------
// k4: add block offsets -> global exclusive offs; init cursor = offs.
// ---------------------------------------------------------------------------
__global__ __launch_bounds__(256) void add_offsets_kernel(
    int* __restrict__ offs, const int* __restrict__ blocksum, int* __restrict__ cursor)
{
    int idx = blockIdx.x * blockDim.x + threadIdx.x;
    if (idx < N_NODES) {
        int v = offs[idx] + blocksum[idx / SCAN_CHUNK];
        offs[idx]  = v;
        cursor[idx] = v;
    }
}

// ---------------------------------------------------------------------------
// k5: scatter edge source indices into CSR slots (counting-sort placement).
// ---------------------------------------------------------------------------
__global__ __launch_bounds__(256) void build_csr_kernel(
    const int* __restrict__ src, const int* __restrict__ dst,
    int* __restrict__ cursor, int* __restrict__ csr_src, int E)
{
    int e = blockIdx.x * blockDim.x + threadIdx.x;
    if (e < E) {
        int pos = atomicAdd(&cursor[dst[e]], 1);
        csr_src[pos] = src[e];
    }
}

// ---------------------------------------------------------------------------
// k6: fused gather + renorm + linear.  Grid-stride, one wave per node per
// iteration, lane = dim.
//   - W row held in REGISTERS per lane (loaded once per wave via a padded
//     LDS transpose: stage Wt[k*65+o]=W[o][k] -> banks k%32 (free); read
//     Wt[k*65+lane] -> banks (k+lane)%32 (free)).  Zero per-node W traffic.
//   - acc broadcast via 1 ds_write_b32 + 16 broadcast ds_read_b128 per node
//     (replaces 64 ds_bpermute).  LDS ops/node: 128 -> 17.
// ---------------------------------------------------------------------------
__global__ __launch_bounds__(256) void gather_linear_kernel(
    const float* __restrict__ feature,  // [N, 64]
    const float* __restrict__ norm,     // [N]
    const int* __restrict__ offs,       // [N] exclusive start
    const int* __restrict__ endp,       // [N] end (cursor after build_csr)
    const int* __restrict__ csr_src,    // [E]
    const float* __restrict__ W,        // [64, 64] row-major [o][k]
    const float* __restrict__ b,        // [64]
    float* __restrict__ out)            // [N, 64]
{
    __shared__ float Wt[D * DP];        // padded transpose, conflict-free
    __shared__ float accsm[4][D];       // per-wave acc broadcast slot

    for (int i = threadIdx.x; i < D * D; i += blockDim.x) {
        int o = i >> 6, k = i & 63;     // lane == k -> write stride DP: free
        Wt[k * DP + o] = W[o * D + k];
    }
    __syncthreads();

    const int lane = threadIdx.x & 63;
    const int wid  = threadIdx.x >> 6;

    // Pull W row `lane` into registers (64 VGPRs), conflict-free reads.
    float wreg[D];
    #pragma unroll
    for (int k = 0; k < D; ++k) wreg[k] = Wt[k * DP + lane];
    const float blane = b[lane];
    float* const mysm = &accsm[wid][0];

    const int wave   = (blockIdx.x * blockDim.x + threadIdx.x) >> 6;
    const int nwaves = gridDim.x * (blockDim.x >> 6);

    for (int node = wave; node < N_NODES; node += nwaves) {
        int beg = offs[node];
        int end = endp[node];

        // Gather-accumulate, unrolled x4 for memory-level parallelism.
        float acc = 0.f;
        int i = beg;
        for (; i + 4 <= end; i += 4) {
            int s0 = csr_src[i + 0];
            int s1 = csr_src[i + 1];
            int s2 = csr_src[i + 2];
            int s3 = csr_src[i + 3];
            float f0 = feature[s0 * D + lane], n0 = norm[s0];
            float f1 = feature[s1 * D + lane], n1 = norm[s1];
            float f2 = feature[s2 * D + lane], n2 = norm[s2];
            float f3 = feature[s3 * D + lane], n3 = norm[s3];
            acc = fmaf(f0, n0, acc);
            acc = fmaf(f1, n1, acc);
            acc = fmaf(f2, n2, acc);
            acc = fmaf(f3, n3, acc);
        }
        for (; i < end; ++i) {
            int s = csr_src[i];
            acc = fmaf(feature[s * D + lane], norm[s], acc);
        }
        acc *= norm[node];

        // Broadcast acc across the wave via LDS (wave-synchronous: single
        // wave, compiler inserts lgkmcnt wait on the memory dependence).
        mysm[lane] = acc;
        __builtin_amdgcn_wave_barrier();

        float r = blane;
        #pragma unroll
        for (int j = 0; j < D / 4; ++j) {
            float4 a4 = *(const float4*)&mysm[j * 4];   // broadcast b128
            r = fmaf(a4.x, wreg[4 * j + 0], r);
            r = fmaf(a4.y, wreg[4 * j + 1], r);
            r = fmaf(a4.z, wreg[4 * j + 2], r);
            r = fmaf(a4.w, wreg[4 * j + 3], r);
        }
        out[node * D + lane] = r;
        __builtin_amdgcn_wave_barrier();  // keep next node's write after reads
    }
}

extern "C" void kernel_launch(void* const* d_in, const int* in_sizes, int n_in,
                              void* d_out, int out_size, void* d_ws, size_t ws_size,
                              hipStream_t stream)
{
    const float* feature = (const float*)d_in[0];  // [N,64]
    const float* norm    = (const float*)d_in[1];  // [N,1]
    const int*   src     = (const int*)d_in[2];    // [E]
    const int*   dst     = (const int*)d_in[3];    // [E]
    const float* W       = (const float*)d_in[4];  // [64,64]
    const float* b       = (const float*)d_in[5];  // [64]
    float*       out     = (float*)d_out;          // [N,64]

    const int E = in_sizes[2];

    // ws layout (all int32): deg[N] | offs[N] | cursor[N] | blocksum[pad] | csr_src[E]
    int* deg      = (int*)d_ws;
    int* offs     = deg + N_NODES;
    int* cursor   = offs + N_NODES;
    int* blocksum = cursor + N_NODES;
    int* csr_src  = blocksum + ((NUM_SCAN_BLOCKS + 63) & ~63);

    hipMemsetAsync(deg, 0, (size_t)N_NODES * sizeof(int), stream);

    histogram_kernel<<<(E + 255) / 256, 256, 0, stream>>>(dst, deg, E);

    scan_blocks_kernel<<<NUM_SCAN_BLOCKS, SCAN_BLOCK, 0, stream>>>(deg, offs, blocksum);
    scan_blocksums_kernel<<<1, 64, 0, stream>>>(blocksum);
    add_offsets_kernel<<<(N_NODES + 255) / 256, 256, 0, stream>>>(offs, blocksum, cursor);

    build_csr_kernel<<<(E + 255) / 256, 256, 0, stream>>>(src, dst, cursor, csr_src, E);

    // ~8 nodes per wave: 3125 blocks x 4 waves = 12500 waves.
    gather_linear_kernel<<<3125, 256, 0, stream>>>(
        feature, norm, offs, cursor, csr_src, W, b, out);
}